// Round 2
// baseline (1019.074 us; speedup 1.0000x reference)
//
#include <hip/hip_runtime.h>
#include <hip/hip_bf16.h>

// MPNN layer, fp32, restructured:
//   P[n] = [ h2[n]@W1a + b1 | h2[n]@W1c ]           (node_pre)
//   hidden_e = ReLU(P_A[src] + e@W1b + P_C[dst])    (edge kernel, scatter-add to Hsum[dst], deg[dst]+=1)
//   h_new = ReLU(Hsum@(W2@U1a) + deg*(b2@U1a) + h@U1b + c1)@U2 + c2   (update kernel)
// Identities: segment_sum(ReLU(pre)@W2 + b2) = segment_sum(ReLU(pre))@W2 + deg*b2
//             m_sum@U1a = Hsum@(W2@U1a) + deg*(b2@U1a)
//
// R2 structure: every kernel is block-cooperative over ONE shared [64][65]
// LDS tile (16.6 KB/block -> 8 blocks/CU vs 2 before). Waves split matvec
// output channels (acc[16..32] regs) and the edge-scatter range (16 edges
// per wave, not 64). src/dst preloaded into SGPRs before the matvec.

#define EPAD 65   // 64 + 1 pad: column access (lane*65+k) -> (lane+k)%32, conflict-free

// ---------------------------------------------------------------------------
// K0: Wp = W2 @ U1a (64x64),  bvec = b2 @ U1a (64)
// ---------------------------------------------------------------------------
__global__ void combine_kernel(const float* __restrict__ W2, const float* __restrict__ b2,
                               const float* __restrict__ U1, float* __restrict__ Wp,
                               float* __restrict__ bvec) {
    int k = blockIdx.x;        // 0..63
    int cc = threadIdx.x;      // 0..63
    float a = 0.f;
    for (int c = 0; c < 64; ++c) a = fmaf(W2[k * 64 + c], U1[c * 64 + cc], a);
    Wp[k * 64 + cc] = a;
    if (k == 0) {
        float bv = 0.f;
        for (int c = 0; c < 64; ++c) bv = fmaf(b2[c], U1[c * 64 + cc], bv);
        bvec[cc] = bv;
    }
}

// cooperative stage of a 64x64 f32 tile into L[row*EPAD + col], optionally
// mirroring to `copy_out`. 256 threads, 4 float4 per thread, coalesced.
__device__ __forceinline__ void stage_tile(const float* __restrict__ X, size_t R0,
                                           int nvalid, float* __restrict__ L,
                                           float* __restrict__ copy_out) {
    const int t = threadIdx.x;
    if (nvalid == 64) {
#pragma unroll
        for (int i = 0; i < 4; ++i) {
            int idx = i * 256 + t;              // 0..1023
            int row = idx >> 4, c4 = idx & 15;
            const float4 v = ((const float4*)(X + (R0 + row) * 64))[c4];
            if (copy_out) ((float4*)(copy_out + (R0 + row) * 64))[c4] = v;
            float* p = &L[row * EPAD + c4 * 4];
            p[0] = v.x; p[1] = v.y; p[2] = v.z; p[3] = v.w;
        }
    } else {
        const int wid = t >> 6, lane = t & 63;
        for (int r = wid; r < nvalid; r += 4) {
            float v = X[(R0 + r) * 64 + lane];
            if (copy_out) copy_out[(R0 + r) * 64 + lane] = v;
            L[r * EPAD + lane] = v;
        }
    }
}

// ---------------------------------------------------------------------------
// K1: node precompute. P[n][0:64] = h2@W1a + b1 ; P[n][64:128] = h2@W1c
// block = one 64-row tile; wave w computes output channels [w*32, w*32+32).
// ---------------------------------------------------------------------------
__global__ __launch_bounds__(256) void node_pre_kernel(
    const float* __restrict__ h, const float* __restrict__ rnf,
    const float* __restrict__ W1, const float* __restrict__ b1,
    float* __restrict__ P, int N) {
    __shared__ float L[64 * EPAD];
    const int t = threadIdx.x, wid = t >> 6, lane = t & 63;
    const size_t R0 = (size_t)blockIdx.x * 64;
    const int nvalid = min(64, N - (int)R0);
    const int o0 = wid * 32;               // 0,32 -> A-half; 64,96 -> C-half

    float acc[32];
#pragma unroll
    for (int j = 0; j < 32; ++j) acc[j] = 0.f;

    for (int ih = 0; ih < 2; ++ih) {
        stage_tile(ih ? rnf : h, R0, nvalid, L, nullptr);
        __syncthreads();
        // weight base: A uses W1 rows ih*64.., col o0; C uses rows 192+ih*64.., col o0-64
        const float* W = (o0 < 64) ? (W1 + (size_t)(ih * 64) * 64 + o0)
                                   : (W1 + (size_t)(192 + ih * 64) * 64 + (o0 - 64));
        for (int k = 0; k < 64; ++k) {
            float x = L[lane * EPAD + k];   // lane = row
#pragma unroll
            for (int j = 0; j < 32; ++j) acc[j] = fmaf(x, W[k * 64 + j], acc[j]);
        }
        __syncthreads();
    }
    if (o0 < 64) {
#pragma unroll
        for (int j = 0; j < 32; ++j) acc[j] += b1[o0 + j];
    }
    if (lane < nvalid) {
        float* dst = P + (R0 + lane) * 128 + o0;
#pragma unroll
        for (int j4 = 0; j4 < 8; ++j4)
            ((float4*)dst)[j4] = make_float4(acc[4 * j4], acc[4 * j4 + 1],
                                             acc[4 * j4 + 2], acc[4 * j4 + 3]);
    }
}

// ---------------------------------------------------------------------------
// K2: edge kernel. Block = 64-edge tile.
//   stage e (+copy out) -> Eb = e@W1b (wave w: channels w*16..; lane=edge)
//   -> transpose Eb in LDS -> wave w scatters edges w*16..w*16+15 (lane=channel).
// ---------------------------------------------------------------------------
__global__ __launch_bounds__(256) void edge_kernel(
    const float* __restrict__ e, const int* __restrict__ src, const int* __restrict__ dst,
    const float* __restrict__ W1, const float* __restrict__ P,
    float* __restrict__ Hsum, float* __restrict__ deg,
    float* __restrict__ e_out, int E) {
    __shared__ float L[64 * EPAD];
    const int t = threadIdx.x, wid = t >> 6, lane = t & 63;
    const size_t E0 = (size_t)blockIdx.x * 64;
    const int evalid = min(64, E - (int)E0);

    stage_tile(e, E0, evalid, L, e_out);

    // preload this wave's src/dst (uniform -> SGPRs) while staging completes
    int srs[16], drs[16];
#pragma unroll
    for (int j = 0; j < 16; ++j) {
        int r = wid * 16 + j;
        bool ok = r < evalid;
        srs[j] = ok ? src[E0 + r] : 0;
        drs[j] = ok ? dst[E0 + r] : 0;
    }
    __syncthreads();

    // Eb[lane(edge)][o0+j] ; o0 = wid*16
    const int o0 = wid * 16;
    float acc[16];
#pragma unroll
    for (int j = 0; j < 16; ++j) acc[j] = 0.f;
    const float* Wb = W1 + (size_t)128 * 64 + o0;   // W1 rows 128..191 (e segment)
    for (int k = 0; k < 64; ++k) {
        float x = L[lane * EPAD + k];
#pragma unroll
        for (int j = 0; j < 16; ++j) acc[j] = fmaf(x, Wb[k * 64 + j], acc[j]);
    }
    __syncthreads();
    // transpose: L[channel][edge]
#pragma unroll
    for (int j = 0; j < 16; ++j) L[(o0 + j) * EPAD + lane] = acc[j];
    __syncthreads();

    // scatter: wave w owns edges w*16 .. w*16+15; lane = channel
    const int rEnd = min(evalid - o0, 16);
    for (int j = 0; j < rEnd; ++j) {
        const int r = o0 + j;
        const int sr = srs[j], dr = drs[j];
        float hv = L[lane * EPAD + r]                    // Eb[r][lane]
                 + P[(size_t)sr * 128 + lane]            // A' (incl b1)
                 + P[(size_t)dr * 128 + 64 + lane];      // C
        hv = fmaxf(hv, 0.f);
        unsafeAtomicAdd(&Hsum[(size_t)dr * 64 + lane], hv);
        if (lane == 0) unsafeAtomicAdd(&deg[dr], 1.0f);
    }
}

// ---------------------------------------------------------------------------
// K3: update. h1 = ReLU(Hsum@Wp + deg*bvec + h@U1b + c1); out = h1@U2 + c2
// block = 64-row tile; wave w computes channels w*16.. in both layers.
// ---------------------------------------------------------------------------
__global__ __launch_bounds__(256) void update_kernel(
    const float* __restrict__ Hsum, const float* __restrict__ deg, const float* __restrict__ h,
    const float* __restrict__ Wp, const float* __restrict__ bvec,
    const float* __restrict__ U1, const float* __restrict__ c1,
    const float* __restrict__ U2, const float* __restrict__ c2,
    float* __restrict__ out, int N) {
    __shared__ float L[64 * EPAD];
    const int t = threadIdx.x, wid = t >> 6, lane = t & 63;
    const size_t R0 = (size_t)blockIdx.x * 64;
    const int nvalid = min(64, N - (int)R0);
    const int o0 = wid * 16;

    float acc[16];
#pragma unroll
    for (int j = 0; j < 16; ++j) acc[j] = 0.f;

    for (int ih = 0; ih < 2; ++ih) {
        stage_tile(ih ? h : Hsum, R0, nvalid, L, nullptr);
        __syncthreads();
        const float* W = ih ? (U1 + (size_t)64 * 64 + o0) : (Wp + o0);
        for (int k = 0; k < 64; ++k) {
            float x = L[lane * EPAD + k];   // lane = row
#pragma unroll
            for (int j = 0; j < 16; ++j) acc[j] = fmaf(x, W[k * 64 + j], acc[j]);
        }
        __syncthreads();
    }

    const float dg = (lane < nvalid) ? deg[R0 + lane] : 0.f;   // lane = row
    // h1 (ReLU), store transposed [channel][row]
#pragma unroll
    for (int j = 0; j < 16; ++j)
        L[(o0 + j) * EPAD + lane] = fmaxf(fmaf(dg, bvec[o0 + j], acc[j] + c1[o0 + j]), 0.f);
    __syncthreads();

    // layer 2: acc2[j] = c2 + sum_k h1[row=lane][k] * U2[k][o0+j]
    float acc2[16];
#pragma unroll
    for (int j = 0; j < 16; ++j) acc2[j] = c2[o0 + j];
    for (int k = 0; k < 64; ++k) {
        float x = L[k * EPAD + lane];       // h1[row=lane][k]; banks (k+lane)%32 - free
#pragma unroll
        for (int j = 0; j < 16; ++j) acc2[j] = fmaf(x, U2[k * 64 + o0 + j], acc2[j]);
    }
    if (lane < nvalid) {
        float* dst = out + (R0 + lane) * 64 + o0;
#pragma unroll
        for (int j4 = 0; j4 < 4; ++j4)
            ((float4*)dst)[j4] = make_float4(acc2[4 * j4], acc2[4 * j4 + 1],
                                             acc2[4 * j4 + 2], acc2[4 * j4 + 3]);
    }
}

// ---------------------------------------------------------------------------
extern "C" void kernel_launch(void* const* d_in, const int* in_sizes, int n_in,
                              void* d_out, int out_size, void* d_ws, size_t ws_size,
                              hipStream_t stream) {
    const float* h   = (const float*)d_in[0];
    const float* e   = (const float*)d_in[1];
    const float* rnf = (const float*)d_in[2];
    const int*   src = (const int*)d_in[3];
    const int*   dst = (const int*)d_in[4];
    const float* W1  = (const float*)d_in[5];
    const float* b1  = (const float*)d_in[6];
    const float* W2  = (const float*)d_in[7];
    const float* b2  = (const float*)d_in[8];
    const float* U1  = (const float*)d_in[9];
    const float* c1  = (const float*)d_in[10];
    const float* U2  = (const float*)d_in[11];
    const float* c2  = (const float*)d_in[12];

    const int N = in_sizes[0] / 64;
    const int E = in_sizes[1] / 64;

    float* out_h = (float*)d_out;
    float* out_e = out_h + (size_t)N * 64;

    float* P    = (float*)d_ws;              // N*128
    float* Hsum = P + (size_t)N * 128;       // N*64
    float* degp = Hsum + (size_t)N * 64;     // N
    float* Wp   = degp + N;                  // 64*64
    float* bvec = Wp + 64 * 64;              // 64

    hipMemsetAsync(Hsum, 0, (size_t)N * 64 * sizeof(float), stream);
    hipMemsetAsync(degp, 0, (size_t)N * sizeof(float), stream);

    combine_kernel<<<64, 64, 0, stream>>>(W2, b2, U1, Wp, bvec);

    const int ntiles = (N + 63) / 64;
    node_pre_kernel<<<ntiles, 256, 0, stream>>>(h, rnf, W1, b1, P, N);

    const int etiles = (E + 63) / 64;
    edge_kernel<<<etiles, 256, 0, stream>>>(e, src, dst, W1, P, Hsum, degp, out_e, E);

    update_kernel<<<ntiles, 256, 0, stream>>>(Hsum, degp, h, Wp, bvec, U1, c1, U2, c2, out_h, N);
}

// Round 4
// 619.476 us; speedup vs baseline: 1.6451x; 1.6451x over previous
//
#include <hip/hip_runtime.h>
#include <hip/hip_bf16.h>

// MPNN layer, fp32, restructured:
//   P[n] = [ h2[n]@W1a + b1 | h2[n]@W1c ]           (node_pre)
//   hidden_e = ReLU(P_A[src] + e@W1b + P_C[dst])    (edge kernel -> atomic Hsum[dst])
//   deg[dst] += 1                                    (deg kernel)
//   h_new = ReLU(Hsum@(W2@U1a) + deg*(b2@U1a) + h@U1b + c1)@U2 + c2   (update)
// Identities: segment_sum(ReLU(pre)@W2 + b2) = segment_sum(ReLU(pre))@W2 + deg*b2
//             m_sum@U1a = Hsum@(W2@U1a) + deg*(b2@U1a)
//
// R3 (resubmitted R4 — acquisition timeout, never ran): latency attack.
//  - P gathers issued at edge-kernel ENTRY (16 loads in flight through
//    staging+matvec), pre-summed into 8 regs.
//  - readfirstlane(wave id) so weight/index addressing is provably uniform
//    -> s_load (scalar) instead of broadcast vector loads.
//  - ds_read_b128 matvec operand reads (stage stride 68 = 16B-aligned rows,
//    conflict-free for b128; transposes use stride 65, conflict-free scalar).
//  - 512-thread blocks; deg in its own coalesced kernel.

#define SPAD 68   // stage stride (floats): 272B rows -> aligned b128, 8-lane bank spread
#define TPAD 65   // transpose stride: (row+col)%32 banks -> conflict-free scalar access

// ---------------------------------------------------------------------------
// K0: Wp = W2 @ U1a (64x64),  bvec = b2 @ U1a (64)
// ---------------------------------------------------------------------------
__global__ void combine_kernel(const float* __restrict__ W2, const float* __restrict__ b2,
                               const float* __restrict__ U1, float* __restrict__ Wp,
                               float* __restrict__ bvec) {
    int k = blockIdx.x;        // 0..63
    int cc = threadIdx.x;      // 0..63
    float a = 0.f;
    for (int c = 0; c < 64; ++c) a = fmaf(W2[k * 64 + c], U1[c * 64 + cc], a);
    Wp[k * 64 + cc] = a;
    if (k == 0) {
        float bv = 0.f;
        for (int c = 0; c < 64; ++c) bv = fmaf(b2[c], U1[c * 64 + cc], bv);
        bvec[cc] = bv;
    }
}

// K_deg: deg[dst[i]] += 1, coalesced index read
__global__ __launch_bounds__(256) void deg_kernel(const int* __restrict__ dst,
                                                  float* __restrict__ deg, int E) {
    int i = blockIdx.x * 256 + threadIdx.x;
    if (i < E) unsafeAtomicAdd(&deg[dst[i]], 1.0f);
}

// cooperative stage of a 64x64 f32 tile into L[row*SPAD + col] (b128-friendly)
template <int NT>
__device__ __forceinline__ void stage_tile(const float* __restrict__ X, size_t R0,
                                           int nvalid, float* __restrict__ L) {
    const int t = threadIdx.x;
    if (nvalid == 64) {
#pragma unroll
        for (int i = 0; i < 1024 / NT; ++i) {
            int idx = i * NT + t;
            int row = idx >> 4, c4 = idx & 15;
            const float4 v = ((const float4*)(X + (R0 + row) * 64))[c4];
            *(float4*)(L + row * SPAD + c4 * 4) = v;
        }
    } else {
        const int w = t >> 6, lane = t & 63;
        for (int r = w; r < nvalid; r += NT / 64)
            L[r * SPAD + lane] = X[(R0 + r) * 64 + lane];
    }
}

// ---------------------------------------------------------------------------
// K1: node precompute. Block = 64-row tile, 8 waves; wave w -> P cols w*16..+15
// (w<4: A-half of W1 (+b1); w>=4: C-half). lane = row.
// ---------------------------------------------------------------------------
__global__ __launch_bounds__(512) void node_pre_kernel(
    const float* __restrict__ h, const float* __restrict__ rnf,
    const float* __restrict__ W1, const float* __restrict__ b1,
    float* __restrict__ P, int N) {
    __shared__ __align__(16) float L[64 * SPAD];
    const int t = threadIdx.x, lane = t & 63;
    const int w = __builtin_amdgcn_readfirstlane(t >> 6);   // provably uniform
    const int o0 = w * 16;                                  // P output column base
    const size_t R0 = (size_t)blockIdx.x * 64;
    const int nvalid = min(64, N - (int)R0);

    float acc[16];
#pragma unroll
    for (int j = 0; j < 16; ++j) acc[j] = 0.f;

    for (int ih = 0; ih < 2; ++ih) {
        if (ih) __syncthreads();                 // L still being read by matvec
        stage_tile<512>(ih ? rnf : h, R0, nvalid, L);
        __syncthreads();
        const float* W = (w < 4) ? (W1 + (size_t)(ih * 64) * 64 + o0)
                                 : (W1 + (size_t)(192 + ih * 64) * 64 + (o0 - 64));
        const float4* Lr = (const float4*)(L + lane * SPAD);
#pragma unroll
        for (int k4 = 0; k4 < 16; ++k4) {
            const float4 x4 = Lr[k4];
            const float* Wk = W + (size_t)k4 * 256;          // 4 rows of 64
#pragma unroll
            for (int j = 0; j < 16; ++j) acc[j] = fmaf(x4.x, Wk[j], acc[j]);
#pragma unroll
            for (int j = 0; j < 16; ++j) acc[j] = fmaf(x4.y, Wk[64 + j], acc[j]);
#pragma unroll
            for (int j = 0; j < 16; ++j) acc[j] = fmaf(x4.z, Wk[128 + j], acc[j]);
#pragma unroll
            for (int j = 0; j < 16; ++j) acc[j] = fmaf(x4.w, Wk[192 + j], acc[j]);
        }
    }
    if (w < 4) {
#pragma unroll
        for (int j = 0; j < 16; ++j) acc[j] += b1[o0 + j];
    }
    if (lane < nvalid) {
        float* dstp = P + (R0 + lane) * 128 + o0;
#pragma unroll
        for (int j4 = 0; j4 < 4; ++j4)
            ((float4*)dstp)[j4] = make_float4(acc[4 * j4], acc[4 * j4 + 1],
                                              acc[4 * j4 + 2], acc[4 * j4 + 3]);
    }
}

// ---------------------------------------------------------------------------
// K2: edge kernel. Block = 64-edge tile, 8 waves.
// Entry: issue 16 P-gathers (edges w*8..w*8+7) -> retire under staging+matvec.
// Matvec: wave w computes Eb channels w*8..+7 for all 64 edges (lane=edge).
// Scatter: wave w handles edges w*8..+7, lane=channel, 1 atomic row each.
// ---------------------------------------------------------------------------
__global__ __launch_bounds__(512) void edge_kernel(
    const float* __restrict__ e, const int* __restrict__ src, const int* __restrict__ dst,
    const float* __restrict__ W1, const float* __restrict__ P,
    float* __restrict__ Hsum, float* __restrict__ e_out, int E) {
    __shared__ __align__(16) float L[64 * SPAD];
    const int t = threadIdx.x, lane = t & 63;
    const int w = __builtin_amdgcn_readfirstlane(t >> 6);
    const int o0 = w * 8;                       // channel base AND edge base
    const size_t E0 = (size_t)blockIdx.x * 64;
    const int evalid = min(64, E - (int)E0);

    if (evalid == 64) {
        // ---- issue stage loads (2 float4/thread) ----
        const float4* esrc = (const float4*)(e + E0 * 64);
        const int idx0 = t, idx1 = 512 + t;
        const float4 v0 = esrc[idx0];
        const float4 v1 = esrc[idx1];
        // ---- issue 16 gathers immediately (uniform index -> saddr form) ----
        int srs[8], drs[8];
#pragma unroll
        for (int j = 0; j < 8; ++j) {
            srs[j] = src[E0 + o0 + j];
            drs[j] = dst[E0 + o0 + j];
        }
        float pa[8], pc[8];
#pragma unroll
        for (int j = 0; j < 8; ++j) pa[j] = P[(size_t)srs[j] * 128 + lane];
#pragma unroll
        for (int j = 0; j < 8; ++j) pc[j] = P[(size_t)drs[j] * 128 + 64 + lane];
        // ---- e_out copy + LDS stage (waits only on v0/v1) ----
        float4* edst = (float4*)(e_out + E0 * 64);
        edst[idx0] = v0;
        edst[idx1] = v1;
        {
            int r0 = idx0 >> 4, c0 = idx0 & 15;
            int r1 = idx1 >> 4, c1 = idx1 & 15;
            *(float4*)(L + r0 * SPAD + c0 * 4) = v0;
            *(float4*)(L + r1 * SPAD + c1 * 4) = v1;
        }
        // pre-sum gathers: 8 live regs through matvec instead of 16
        float ps[8];
#pragma unroll
        for (int j = 0; j < 8; ++j) ps[j] = pa[j] + pc[j];
        __syncthreads();

        // ---- matvec: Eb[edge=lane][o0+j] ----
        float acc[8];
#pragma unroll
        for (int j = 0; j < 8; ++j) acc[j] = 0.f;
        const float* Wb = W1 + (size_t)128 * 64 + o0;        // e-segment of W1
        const float4* Lr = (const float4*)(L + lane * SPAD);
#pragma unroll
        for (int k4 = 0; k4 < 16; ++k4) {
            const float4 x4 = Lr[k4];
            const float* Wk = Wb + (size_t)k4 * 256;
#pragma unroll
            for (int j = 0; j < 8; ++j) acc[j] = fmaf(x4.x, Wk[j], acc[j]);
#pragma unroll
            for (int j = 0; j < 8; ++j) acc[j] = fmaf(x4.y, Wk[64 + j], acc[j]);
#pragma unroll
            for (int j = 0; j < 8; ++j) acc[j] = fmaf(x4.z, Wk[128 + j], acc[j]);
#pragma unroll
            for (int j = 0; j < 8; ++j) acc[j] = fmaf(x4.w, Wk[192 + j], acc[j]);
        }
        __syncthreads();
        // ---- transpose Eb: L[ch*TPAD + edge] (reuses dead e-tile) ----
#pragma unroll
        for (int j = 0; j < 8; ++j) L[(o0 + j) * TPAD + lane] = acc[j];
        __syncthreads();
        // ---- scatter: edge r = o0+j, lane = channel ----
#pragma unroll
        for (int j = 0; j < 8; ++j) {
            float hv = fmaxf(L[lane * TPAD + o0 + j] + ps[j], 0.f);
            unsafeAtomicAdd(&Hsum[(size_t)drs[j] * 64 + lane], hv);
        }
    } else {
        // generic fallback (unused when E % 64 == 0): shuffle-broadcast matvec
        for (int r = w; r < evalid; r += 8) {
            int sr = src[E0 + r], dr = dst[E0 + r];
            float ev = e[(E0 + r) * 64 + lane];
            e_out[(E0 + r) * 64 + lane] = ev;
            float hv = P[(size_t)sr * 128 + lane] + P[(size_t)dr * 128 + 64 + lane];
            const float* Wb = W1 + (size_t)128 * 64;
            for (int k = 0; k < 64; ++k)
                hv = fmaf(__shfl(ev, k, 64), Wb[k * 64 + lane], hv);
            hv = fmaxf(hv, 0.f);
            unsafeAtomicAdd(&Hsum[(size_t)dr * 64 + lane], hv);
        }
    }
}

// ---------------------------------------------------------------------------
// K3: update. Block = 64-row tile, 8 waves; wave w -> out cols w*8..+7.
// h1 = ReLU(Hsum@Wp + deg*bvec + h@U1b + c1); out = h1@U2 + c2
// ---------------------------------------------------------------------------
__global__ __launch_bounds__(512) void update_kernel(
    const float* __restrict__ Hsum, const float* __restrict__ deg, const float* __restrict__ h,
    const float* __restrict__ Wp, const float* __restrict__ bvec,
    const float* __restrict__ U1, const float* __restrict__ c1,
    const float* __restrict__ U2, const float* __restrict__ c2,
    float* __restrict__ out, int N) {
    __shared__ __align__(16) float L[64 * SPAD];
    const int t = threadIdx.x, lane = t & 63;
    const int w = __builtin_amdgcn_readfirstlane(t >> 6);
    const int o0 = w * 8;
    const size_t R0 = (size_t)blockIdx.x * 64;
    const int nvalid = min(64, N - (int)R0);

    float acc[8];
#pragma unroll
    for (int j = 0; j < 8; ++j) acc[j] = 0.f;

    for (int ih = 0; ih < 2; ++ih) {
        if (ih) __syncthreads();
        stage_tile<512>(ih ? h : Hsum, R0, nvalid, L);
        __syncthreads();
        const float* W = ih ? (U1 + (size_t)64 * 64 + o0) : (Wp + o0);
        const float4* Lr = (const float4*)(L + lane * SPAD);
#pragma unroll
        for (int k4 = 0; k4 < 16; ++k4) {
            const float4 x4 = Lr[k4];
            const float* Wk = W + (size_t)k4 * 256;
#pragma unroll
            for (int j = 0; j < 8; ++j) acc[j] = fmaf(x4.x, Wk[j], acc[j]);
#pragma unroll
            for (int j = 0; j < 8; ++j) acc[j] = fmaf(x4.y, Wk[64 + j], acc[j]);
#pragma unroll
            for (int j = 0; j < 8; ++j) acc[j] = fmaf(x4.z, Wk[128 + j], acc[j]);
#pragma unroll
            for (int j = 0; j < 8; ++j) acc[j] = fmaf(x4.w, Wk[192 + j], acc[j]);
        }
    }
    __syncthreads();                             // matvec done before h1 overwrite

    const float dg = (lane < nvalid) ? deg[R0 + lane] : 0.f;   // lane = row
#pragma unroll
    for (int j = 0; j < 8; ++j)
        L[(o0 + j) * TPAD + lane] = fmaxf(fmaf(dg, bvec[o0 + j], acc[j] + c1[o0 + j]), 0.f);
    __syncthreads();

    // layer 2: acc2[j] = c2 + sum_k h1[row=lane][k] * U2[k][o0+j]
    float acc2[8];
#pragma unroll
    for (int j = 0; j < 8; ++j) acc2[j] = c2[o0 + j];
    for (int k = 0; k < 64; ++k) {
        const float x = L[k * TPAD + lane];      // banks (k+lane)%32: conflict-free
#pragma unroll
        for (int j = 0; j < 8; ++j) acc2[j] = fmaf(x, U2[k * 64 + o0 + j], acc2[j]);
    }
    if (lane < nvalid) {
        float* dstp = out + (R0 + lane) * 64 + o0;
        ((float4*)dstp)[0] = make_float4(acc2[0], acc2[1], acc2[2], acc2[3]);
        ((float4*)dstp)[1] = make_float4(acc2[4], acc2[5], acc2[6], acc2[7]);
    }
}

// ---------------------------------------------------------------------------
extern "C" void kernel_launch(void* const* d_in, const int* in_sizes, int n_in,
                              void* d_out, int out_size, void* d_ws, size_t ws_size,
                              hipStream_t stream) {
    const float* h   = (const float*)d_in[0];
    const float* e   = (const float*)d_in[1];
    const float* rnf = (const float*)d_in[2];
    const int*   src = (const int*)d_in[3];
    const int*   dst = (const int*)d_in[4];
    const float* W1  = (const float*)d_in[5];
    const float* b1  = (const float*)d_in[6];
    const float* W2  = (const float*)d_in[7];
    const float* b2  = (const float*)d_in[8];
    const float* U1  = (const float*)d_in[9];
    const float* c1  = (const float*)d_in[10];
    const float* U2  = (const float*)d_in[11];
    const float* c2  = (const float*)d_in[12];

    const int N = in_sizes[0] / 64;
    const int E = in_sizes[1] / 64;

    float* out_h = (float*)d_out;
    float* out_e = out_h + (size_t)N * 64;

    float* P    = (float*)d_ws;              // N*128
    float* Hsum = P + (size_t)N * 128;       // N*64
    float* degp = Hsum + (size_t)N * 64;     // N
    float* Wp   = degp + N;                  // 64*64
    float* bvec = Wp + 64 * 64;              // 64

    hipMemsetAsync(Hsum, 0, (size_t)N * 64 * sizeof(float), stream);
    hipMemsetAsync(degp, 0, (size_t)N * sizeof(float), stream);

    combine_kernel<<<64, 64, 0, stream>>>(W2, b2, U1, Wp, bvec);
    deg_kernel<<<(E + 255) / 256, 256, 0, stream>>>(dst, degp, E);

    const int ntiles = (N + 63) / 64;
    node_pre_kernel<<<ntiles, 512, 0, stream>>>(h, rnf, W1, b1, P, N);

    const int etiles = (E + 63) / 64;
    edge_kernel<<<etiles, 512, 0, stream>>>(e, src, dst, W1, P, Hsum, out_e, E);

    update_kernel<<<ntiles, 512, 0, stream>>>(Hsum, degp, h, Wp, bvec, U1, c1, U2, c2, out_h, N);
}